// Round 2
// 965.925 us; speedup vs baseline: 1.0446x; 1.0446x over previous
//
#include <hip/hip_runtime.h>

// DeepSeekV3 MoE: B=1 S=2048 H=2048, E=32 (4 groups, top-2 groups, top-4),
// scale 2.5, I=1024 (+shared expert I=1024). fp32 in/out; bf16 MFMA compute.
//
// R2 = R1 resubmit (R1 bench died on container acquire, no kernel signal).
// R1 changes vs baseline (theory: VALU-convert + A-tile bank conflicts + barrier count):
//  - v_cvt_pk_bf16_f32 inline asm replaces manual RNE pack (5x fewer VALU ops)
//  - BK 32 -> 64 in stage1/stage2 (halves barrier/drain count; LDS ~35KB, 4 blocks/CU)
//  - A-tile XOR swizzle (pre-swizzled global source + swizzled ds_read, linear LDS dest
//    as required by global_load_lds): 8/16-way -> 2-way conflicts on A reads
//  - offsets_kernel: serial loop -> wave shuffle scan

#define T_TOK 2048
#define HD 2048
#define NE 32
#define NI 1024
#define NG 4
#define GSZ (NE / NG)
#define SCALE_F 2.5f

typedef unsigned short ushort_t;
typedef __attribute__((ext_vector_type(8))) short bf16x8;
typedef __attribute__((ext_vector_type(4))) float f32x4;

// HW packed f32->bf16 (RNE), 1 instr per 2 floats. No builtin on gfx950; asm per guide.
__device__ inline unsigned cvtpk2(float a, float b) {
  unsigned r;
  asm("v_cvt_pk_bf16_f32 %0, %1, %2" : "=v"(r) : "v"(a), "v"(b));
  return r;
}
__device__ inline ushort_t f2bf1(float f) { return (ushort_t)(cvtpk2(f, f) & 0xffffu); }

#define GLDS(gp, lp) \
  __builtin_amdgcn_global_load_lds((const __attribute__((address_space(1))) void*)(gp), \
                                   (__attribute__((address_space(3))) void*)(lp), 16, 0, 0)

// ---- workspace layout (bytes) ----
#define XB_OFF   0ull                                 // ushort[T*H]       8 MiB
#define CNT_OFF  (XB_OFF + 2ull * T_TOK * HD)         // int[NE]
#define OFFS_OFF (CNT_OFF + 256ull)                   // int[NE+1]
#define TOK_OFF  (OFFS_OFF + 256ull)                  // int[NE*T]
#define BW_OFF   (TOK_OFF + 4ull * NE * T_TOK)        // float[NE*T]
#define SC_OFF   (BW_OFF + 4ull * NE * T_TOK)        // float[T*NE]
#define HR_ROWS  12288                                // sum cnt padded to 128
#define HR_OFF   (SC_OFF + 4ull * T_TOK * NE)         // ushort[HR_ROWS*NI] 24 MiB
#define HS_OFF   (HR_OFF + 2ull * HR_ROWS * NI)       // ushort[T*NI]        4 MiB

// ---- kernel 1: X fp32 -> bf16, zero out, zero counts ----
__global__ __launch_bounds__(256) void prep_kernel(const float* __restrict__ x,
    ushort_t* __restrict__ xb, float* __restrict__ out, int* __restrict__ counts) {
  if (blockIdx.x == 0 && threadIdx.x < NE) counts[threadIdx.x] = 0;
  int n4 = T_TOK * HD / 4;
  for (int i = blockIdx.x * blockDim.x + threadIdx.x; i < n4; i += gridDim.x * blockDim.x) {
    float4 v = ((const float4*)x)[i];
    uint2 p;
    p.x = cvtpk2(v.x, v.y);
    p.y = cvtpk2(v.z, v.w);
    ((uint2*)xb)[i] = p;
    ((float4*)out)[i] = make_float4(0.f, 0.f, 0.f, 0.f);
  }
}

// ---- kernel 2a: logits = X @ gw^T (fp32, tiled LDS GEMM) ----
__global__ __launch_bounds__(256) void logits_kernel(const float* __restrict__ x,
    const float* __restrict__ gw, float* __restrict__ scores) {
  __shared__ float4 gws[32 * 65];
  __shared__ float4 xs[8 * 64];
  int tid = threadIdx.x;
  int t0 = blockIdx.x * 8;
  const float4* x4 = (const float4*)x;
  const float4* g4 = (const float4*)gw;
  int tok = tid >> 5, e = tid & 31;
  float acc = 0.f;
  for (int c = 0; c < 8; c++) {
    int k4 = c * 64;
    for (int j = tid; j < 32 * 64; j += 256)
      gws[(j >> 6) * 65 + (j & 63)] = g4[(size_t)(j >> 6) * (HD / 4) + k4 + (j & 63)];
    for (int j = tid; j < 8 * 64; j += 256)
      xs[j] = x4[(size_t)(t0 + (j >> 6)) * (HD / 4) + k4 + (j & 63)];
    __syncthreads();
#pragma unroll 8
    for (int c4 = 0; c4 < 64; c4++) {
      float4 xv = xs[tok * 64 + c4];
      float4 wv = gws[e * 65 + c4];
      acc += xv.x * wv.x + xv.y * wv.y + xv.z * wv.z + xv.w * wv.w;
    }
    __syncthreads();
  }
  scores[(size_t)(t0 + tok) * NE + e] = acc;
}

// ---- kernel 2b: routing (one thread per token) ----
__global__ __launch_bounds__(256) void route_kernel(const float* __restrict__ scores,
    const float* __restrict__ bias, int* __restrict__ counts,
    int* __restrict__ btok, float* __restrict__ bw) {
  int t = blockIdx.x * 256 + threadIdx.x;
  if (t >= T_TOK) return;
  float s[NE], sb[NE];
#pragma unroll
  for (int e = 0; e < NE; e++) {
    float sig = 1.f / (1.f + expf(-scores[(size_t)t * NE + e]));
    s[e] = sig;
    sb[e] = sig + bias[e];
  }
  float gs[NG];
#pragma unroll
  for (int g = 0; g < NG; g++) {
    float m1 = -1e30f, m2 = -1e30f;
#pragma unroll
    for (int j = 0; j < GSZ; j++) {
      float v = sb[g * GSZ + j];
      if (v > m1) { m2 = m1; m1 = v; } else if (v > m2) { m2 = v; }
    }
    gs[g] = m1 + m2;
  }
  int g0 = 0; float bv = -1e30f;
#pragma unroll
  for (int g = 0; g < NG; g++) if (gs[g] > bv) { bv = gs[g]; g0 = g; }
  int g1 = -1; bv = -1e30f;
#pragma unroll
  for (int g = 0; g < NG; g++) if (g != g0 && gs[g] > bv) { bv = gs[g]; g1 = g; }
  unsigned used = 0;
  int idx[4]; float tw[4]; float sum = 0.f;
#pragma unroll
  for (int k = 0; k < 4; k++) {
    float best = -1e30f; int bi = 0;
#pragma unroll
    for (int e = 0; e < NE; e++) {
      int g = e >> 3;
      float v = (g == g0 || g == g1) ? sb[e] : 0.0f;
      if (!((used >> e) & 1u) && v > best) { best = v; bi = e; }
    }
    used |= 1u << bi;
    idx[k] = bi; tw[k] = s[bi]; sum += s[bi];
  }
  float inv = SCALE_F / (sum + 1e-20f);
#pragma unroll
  for (int k = 0; k < 4; k++) {
    int e = idx[k];
    int pos = atomicAdd(&counts[e], 1);
    btok[(size_t)e * T_TOK + pos] = t;
    bw[(size_t)e * T_TOK + pos] = tw[k] * inv;
  }
}

// ---- kernel 3: padded prefix sums (pad 128), wave scan ----
__global__ void offsets_kernel(const int* __restrict__ counts, int* __restrict__ offs) {
  int lane = threadIdx.x;
  int s = (lane < NE) ? ((counts[lane] + 127) & ~127) : 0;
#pragma unroll
  for (int d = 1; d < 64; d <<= 1) {
    int n = __shfl_up(s, d);
    if (lane >= d) s += n;
  }
  if (lane == 0) offs[0] = 0;
  if (lane < NE) offs[lane + 1] = s;
}

// ---- kernel 4: stage-1: h = silu(X w1^T) * (X w3^T), 128x64 tile, BK=64, bf16 out ----
// grid (NI/64, T/128, NE+1); z==NE -> shared expert
__global__ __launch_bounds__(256) void stage1_kernel(
    const float* __restrict__ w1, const float* __restrict__ w3,
    const float* __restrict__ ws1f, const float* __restrict__ ws3f,
    const ushort_t* __restrict__ xb, const int* __restrict__ counts,
    const int* __restrict__ offs, const int* __restrict__ btok,
    ushort_t* __restrict__ hr, ushort_t* __restrict__ hs) {
  int e = blockIdx.z, mt = blockIdx.y, nt = blockIdx.x;
  int cnt, base;
  const float *W1, *W3;
  ushort_t* ho;
  if (e == NE) {
    cnt = T_TOK; W1 = ws1f; W3 = ws3f; ho = hs; base = 0;
  } else {
    cnt = counts[e];
    if (mt * 128 >= cnt) return;
    W1 = w1 + (size_t)e * NI * HD;
    W3 = w3 + (size_t)e * NI * HD;
    ho = hr; base = offs[e];
  }
  __shared__ __align__(16) ushort_t As[128 * 64];   // linear (global_load_lds), XOR-swz source
  __shared__ __align__(16) ushort_t B1s[64 * 72];   // pad 72 (read-side ~2-way)
  __shared__ __align__(16) ushort_t B3s[64 * 72];
  __shared__ int toks[128];
  int tid = threadIdx.x, wave = tid >> 6, lane = tid & 63;
  if (tid < 128) {
    int m = mt * 128 + tid;
    toks[tid] = (e == NE) ? min(m, T_TOK - 1) : btok[(size_t)e * T_TOK + min(m, cnt - 1)];
  }
  __syncthreads();
  int lm = lane & 15, lq = lane >> 4;
  int nbase = nt * 64;
  // A staging: 4 GLDS/iter; call i covers rows i*32 + wave*8 + (lane>>3), 8 lanes/row.
  // Source chunk pre-swizzled by row&7 so swizzled ds_read is 2-way conflict-free.
  int swz = ((lane & 7) ^ ((lane >> 3) & 7)) * 8;   // row&7 == (lane>>3)&7 here
  const ushort_t* ag[4];
  ushort_t* al[4];
#pragma unroll
  for (int i = 0; i < 4; i++) {
    int r = i * 32 + wave * 8 + (lane >> 3);
    ag[i] = xb + (size_t)toks[r] * HD + swz;
    al[i] = As + i * 2048 + wave * 512 + lane * 8;
  }
  // B staging (fp32 -> bf16 via cvt_pk): thread owns row tid>>2, 16 floats
  int br = tid >> 2, bc = (tid & 3) * 16;
  const float* b1g = W1 + (size_t)(nbase + br) * HD + bc;
  const float* b3g = W3 + (size_t)(nbase + br) * HD + bc;
  ushort_t* b1l = B1s + br * 72 + bc;
  ushort_t* b3l = B3s + br * 72 + bc;

  f32x4 acc1[2][4], acc3[2][4];
#pragma unroll
  for (int i = 0; i < 2; i++)
#pragma unroll
    for (int j = 0; j < 4; j++) {
      acc1[i][j] = (f32x4){0.f, 0.f, 0.f, 0.f};
      acc3[i][j] = (f32x4){0.f, 0.f, 0.f, 0.f};
    }

  for (int kb = 0; kb < HD / 64; kb++) {
    int k0 = kb * 64;
#pragma unroll
    for (int i = 0; i < 4; i++) GLDS(ag[i] + k0, al[i]);
    {
      float4 v0 = *(const float4*)(b1g + k0);
      float4 v1 = *(const float4*)(b1g + k0 + 4);
      float4 v2 = *(const float4*)(b1g + k0 + 8);
      float4 v3 = *(const float4*)(b1g + k0 + 12);
      uint4 p0, p1;
      p0.x = cvtpk2(v0.x, v0.y); p0.y = cvtpk2(v0.z, v0.w);
      p0.z = cvtpk2(v1.x, v1.y); p0.w = cvtpk2(v1.z, v1.w);
      p1.x = cvtpk2(v2.x, v2.y); p1.y = cvtpk2(v2.z, v2.w);
      p1.z = cvtpk2(v3.x, v3.y); p1.w = cvtpk2(v3.z, v3.w);
      *(uint4*)b1l = p0;
      *(uint4*)(b1l + 8) = p1;
    }
    {
      float4 v0 = *(const float4*)(b3g + k0);
      float4 v1 = *(const float4*)(b3g + k0 + 4);
      float4 v2 = *(const float4*)(b3g + k0 + 8);
      float4 v3 = *(const float4*)(b3g + k0 + 12);
      uint4 p0, p1;
      p0.x = cvtpk2(v0.x, v0.y); p0.y = cvtpk2(v0.z, v0.w);
      p0.z = cvtpk2(v1.x, v1.y); p0.w = cvtpk2(v1.z, v1.w);
      p1.x = cvtpk2(v2.x, v2.y); p1.y = cvtpk2(v2.z, v2.w);
      p1.z = cvtpk2(v3.x, v3.y); p1.w = cvtpk2(v3.z, v3.w);
      *(uint4*)b3l = p0;
      *(uint4*)(b3l + 8) = p1;
    }
    __syncthreads();
#pragma unroll
    for (int ks = 0; ks < 2; ks++) {
      int ach = ((ks * 4 + lq) ^ (lm & 7)) * 8;
      bf16x8 a0 = *(const bf16x8*)(As + (wave * 32 + lm) * 64 + ach);
      bf16x8 a1 = *(const bf16x8*)(As + (wave * 32 + 16 + lm) * 64 + ach);
#pragma unroll
      for (int n4 = 0; n4 < 4; n4++) {
        bf16x8 b1 = *(const bf16x8*)(B1s + (n4 * 16 + lm) * 72 + ks * 32 + lq * 8);
        bf16x8 b3 = *(const bf16x8*)(B3s + (n4 * 16 + lm) * 72 + ks * 32 + lq * 8);
        acc1[0][n4] = __builtin_amdgcn_mfma_f32_16x16x32_bf16(a0, b1, acc1[0][n4], 0, 0, 0);
        acc1[1][n4] = __builtin_amdgcn_mfma_f32_16x16x32_bf16(a1, b1, acc1[1][n4], 0, 0, 0);
        acc3[0][n4] = __builtin_amdgcn_mfma_f32_16x16x32_bf16(a0, b3, acc3[0][n4], 0, 0, 0);
        acc3[1][n4] = __builtin_amdgcn_mfma_f32_16x16x32_bf16(a1, b3, acc3[1][n4], 0, 0, 0);
      }
    }
    __syncthreads();
  }
  // epilogue: silu(g)*u; C/D layout col=lane&15, row=lq*4+r
#pragma unroll
  for (int i = 0; i < 2; i++)
#pragma unroll
    for (int n4 = 0; n4 < 4; n4++)
#pragma unroll
      for (int r = 0; r < 4; r++) {
        int row = wave * 32 + i * 16 + lq * 4 + r;
        float g = acc1[i][n4][r], u = acc3[i][n4][r];
        float hv = (g / (1.f + __expf(-g))) * u;
        ho[(size_t)(base + mt * 128 + row) * NI + nbase + n4 * 16 + lm] = f2bf1(hv);
      }
}

// ---- kernel 5: stage-2: out += w * (h w2^T), 128x128 tile, BK=64, atomic ----
// grid (HD/128, T/128, NE+1)
__global__ __launch_bounds__(256) void stage2_kernel(
    const float* __restrict__ w2, const float* __restrict__ ws2f,
    const ushort_t* __restrict__ hr, const ushort_t* __restrict__ hs,
    const int* __restrict__ counts, const int* __restrict__ offs,
    const int* __restrict__ btok, const float* __restrict__ bw,
    float* __restrict__ out) {
  int e = blockIdx.z, mt = blockIdx.y, nt = blockIdx.x;
  int cnt, base;
  const float* W2;
  const ushort_t* hsrc;
  if (e == NE) {
    cnt = T_TOK; W2 = ws2f; hsrc = hs; base = 0;
  } else {
    cnt = counts[e];
    if (mt * 128 >= cnt) return;
    W2 = w2 + (size_t)e * HD * NI;
    hsrc = hr; base = offs[e];
  }
  __shared__ __align__(16) ushort_t As[128 * 64];
  __shared__ __align__(16) ushort_t Bs[128 * 72];
  __shared__ int toks[128];
  __shared__ float wts[128];
  int tid = threadIdx.x, wave = tid >> 6, lane = tid & 63;
  if (tid < 128) {
    int m = mt * 128 + tid;
    if (e == NE) { toks[tid] = m; wts[tid] = 1.f; }
    else {
      int mm = min(m, cnt - 1);
      toks[tid] = btok[(size_t)e * T_TOK + mm];
      wts[tid] = bw[(size_t)e * T_TOK + mm];
    }
  }
  __syncthreads();
  int lm = lane & 15, lq = lane >> 4;
  int wr = wave >> 1, wc = wave & 1;
  // A staging: contiguous compacted rows, pre-swizzled source
  int swz = ((lane & 7) ^ ((lane >> 3) & 7)) * 8;
  const ushort_t* agbase = hsrc + (size_t)(base + mt * 128) * NI;
  const ushort_t* ag[4];
  ushort_t* al[4];
#pragma unroll
  for (int i = 0; i < 4; i++) {
    int r = i * 32 + wave * 8 + (lane >> 3);
    ag[i] = agbase + (size_t)r * NI + swz;
    al[i] = As + i * 2048 + wave * 512 + lane * 8;
  }
  // B staging (fp32 -> bf16): thread owns rows br, br+64; 16 floats each
  int br = tid >> 2, bc = (tid & 3) * 16;
  const float* bg0 = W2 + (size_t)(nt * 128 + br) * NI + bc;
  const float* bg1 = W2 + (size_t)(nt * 128 + 64 + br) * NI + bc;
  ushort_t* bl0 = Bs + br * 72 + bc;
  ushort_t* bl1 = Bs + (64 + br) * 72 + bc;

  f32x4 acc[4][4];
#pragma unroll
  for (int i = 0; i < 4; i++)
#pragma unroll
    for (int j = 0; j < 4; j++) acc[i][j] = (f32x4){0.f, 0.f, 0.f, 0.f};

  for (int kb = 0; kb < NI / 64; kb++) {
    int k0 = kb * 64;
#pragma unroll
    for (int i = 0; i < 4; i++) GLDS(ag[i] + k0, al[i]);
    {
      float4 v0 = *(const float4*)(bg0 + k0);
      float4 v1 = *(const float4*)(bg0 + k0 + 4);
      float4 v2 = *(const float4*)(bg0 + k0 + 8);
      float4 v3 = *(const float4*)(bg0 + k0 + 12);
      uint4 p0, p1;
      p0.x = cvtpk2(v0.x, v0.y); p0.y = cvtpk2(v0.z, v0.w);
      p0.z = cvtpk2(v1.x, v1.y); p0.w = cvtpk2(v1.z, v1.w);
      p1.x = cvtpk2(v2.x, v2.y); p1.y = cvtpk2(v2.z, v2.w);
      p1.z = cvtpk2(v3.x, v3.y); p1.w = cvtpk2(v3.z, v3.w);
      *(uint4*)bl0 = p0;
      *(uint4*)(bl0 + 8) = p1;
    }
    {
      float4 v0 = *(const float4*)(bg1 + k0);
      float4 v1 = *(const float4*)(bg1 + k0 + 4);
      float4 v2 = *(const float4*)(bg1 + k0 + 8);
      float4 v3 = *(const float4*)(bg1 + k0 + 12);
      uint4 p0, p1;
      p0.x = cvtpk2(v0.x, v0.y); p0.y = cvtpk2(v0.z, v0.w);
      p0.z = cvtpk2(v1.x, v1.y); p0.w = cvtpk2(v1.z, v1.w);
      p1.x = cvtpk2(v2.x, v2.y); p1.y = cvtpk2(v2.z, v2.w);
      p1.z = cvtpk2(v3.x, v3.y); p1.w = cvtpk2(v3.z, v3.w);
      *(uint4*)bl1 = p0;
      *(uint4*)(bl1 + 8) = p1;
    }
    __syncthreads();
#pragma unroll
    for (int ks = 0; ks < 2; ks++) {
      int ach = ((ks * 4 + lq) ^ (lm & 7)) * 8;
      bf16x8 a[4], b[4];
#pragma unroll
      for (int i = 0; i < 4; i++)
        a[i] = *(const bf16x8*)(As + (wr * 64 + i * 16 + lm) * 64 + ach);
#pragma unroll
      for (int j = 0; j < 4; j++)
        b[j] = *(const bf16x8*)(Bs + (wc * 64 + j * 16 + lm) * 72 + ks * 32 + lq * 8);
#pragma unroll
      for (int i = 0; i < 4; i++)
#pragma unroll
        for (int j = 0; j < 4; j++)
          acc[i][j] = __builtin_amdgcn_mfma_f32_16x16x32_bf16(a[i], b[j], acc[i][j], 0, 0, 0);
    }
    __syncthreads();
  }
#pragma unroll
  for (int i = 0; i < 4; i++)
#pragma unroll
    for (int j = 0; j < 4; j++)
#pragma unroll
      for (int r = 0; r < 4; r++) {
        int m = wr * 64 + i * 16 + lq * 4 + r;
        if (mt * 128 + m < cnt) {
          float v = acc[i][j][r] * wts[m];
          atomicAdd(out + (size_t)toks[m] * HD + nt * 128 + wc * 64 + j * 16 + lm, v);
        }
      }
}

extern "C" void kernel_launch(void* const* d_in, const int* in_sizes, int n_in,
                              void* d_out, int out_size, void* d_ws, size_t ws_size,
                              hipStream_t stream) {
  const float* x    = (const float*)d_in[0];
  const float* gw   = (const float*)d_in[1];
  const float* bias = (const float*)d_in[2];
  const float* w1   = (const float*)d_in[3];
  const float* w3   = (const float*)d_in[4];
  const float* w2   = (const float*)d_in[5];
  const float* ws1  = (const float*)d_in[6];
  const float* ws3  = (const float*)d_in[7];
  const float* ws2  = (const float*)d_in[8];
  float* out = (float*)d_out;
  char* ws = (char*)d_ws;

  ushort_t* xb  = (ushort_t*)(ws + XB_OFF);
  int* counts   = (int*)(ws + CNT_OFF);
  int* offs     = (int*)(ws + OFFS_OFF);
  int* btok     = (int*)(ws + TOK_OFF);
  float* bwts   = (float*)(ws + BW_OFF);
  float* scores = (float*)(ws + SC_OFF);
  ushort_t* hr  = (ushort_t*)(ws + HR_OFF);
  ushort_t* hs  = (ushort_t*)(ws + HS_OFF);

  prep_kernel<<<1024, 256, 0, stream>>>(x, xb, out, counts);
  logits_kernel<<<T_TOK / 8, 256, 0, stream>>>(x, gw, scores);
  route_kernel<<<T_TOK / 256, 256, 0, stream>>>(scores, bias, counts, btok, bwts);
  offsets_kernel<<<1, 64, 0, stream>>>(counts, offs);
  stage1_kernel<<<dim3(NI / 64, T_TOK / 128, NE + 1), 256, 0, stream>>>(
      w1, w3, ws1, ws3, xb, counts, offs, btok, hr, hs);
  stage2_kernel<<<dim3(HD / 128, T_TOK / 128, NE + 1), 256, 0, stream>>>(
      w2, ws2, hr, hs, counts, offs, btok, bwts, out);
}